// Round 14
// baseline (1141.347 us; speedup 1.0000x reference)
//
#include <hip/hip_runtime.h>
#include <cstddef>
#include <cstdint>

#define NH 16
#define HD 64
#define SLEN 1024
#define NB 64
#define DMODEL 1024

// ===== MEASUREMENT ROUND #2 =====
// Idempotent self-reps push each kernel past the ~155us top-5 visibility
// threshold so rocprof finally shows per-kernel counters. asm memory clobber
// per rep stops load-CSE across reps. k2 unchanged (measured in R9).
#define K0_REP 24
#define K1_REP 24
#define KSM_REP 40
#define K3_REP 4
#define K4_REP 12
#define REP_FENCE() asm volatile("" ::: "memory")

#define DOT4_ACC(acc, k, q) \
  acc = fmaf((k).x, (q).x, fmaf((k).y, (q).y, fmaf((k).z, (q).z, fmaf((k).w, (q).w, (acc)))))

#define FMA4_BCAST(accv, qv, w0_, w1_, w2_, w3_) do { \
  (accv).x = fmaf((qv).x, (w0_).x, fmaf((qv).y, (w1_).x, fmaf((qv).z, (w2_).x, fmaf((qv).w, (w3_).x, (accv).x)))); \
  (accv).y = fmaf((qv).x, (w0_).y, fmaf((qv).y, (w1_).y, fmaf((qv).z, (w2_).y, fmaf((qv).w, (w3_).y, (accv).y)))); \
  (accv).z = fmaf((qv).x, (w0_).z, fmaf((qv).y, (w1_).z, fmaf((qv).z, (w2_).z, fmaf((qv).w, (w3_).z, (accv).z)))); \
  (accv).w = fmaf((qv).x, (w0_).w, fmaf((qv).y, (w1_).w, fmaf((qv).z, (w2_).w, fmaf((qv).w, (w3_).w, (accv).w)))); \
} while (0)

#define VMCNT_WAIT(n) asm volatile("s_waitcnt vmcnt(" #n ")" ::: "memory")
#define BAR() asm volatile("s_barrier" ::: "memory")

__device__ __forceinline__ float wred_sum(float v) {
#pragma unroll
  for (int off = 32; off; off >>= 1) v += __shfl_xor(v, off, 64);
  return v;
}

__device__ __forceinline__ void gload16(const float* g, float* lds_base) {
  __builtin_amdgcn_global_load_lds(
      (const __attribute__((address_space(1))) void*)g,
      (__attribute__((address_space(3))) void*)lds_base, 16, 0, 0);
}

// K0 (R13 body, repped): qp[b][j] = sum_c query[b][c] * Wq[j][c].
__global__ __launch_bounds__(256) void k0_qp(const float* __restrict__ query,
                                             const float* __restrict__ Wq,
                                             float* __restrict__ qp) {
  const int tid = threadIdx.x;
  const int w = tid >> 6, l = tid & 63;
  const int jq = blockIdx.x & 255;
  const int bq = blockIdx.x >> 8;      // 0..3
  const int j = jq * 4 + w;            // 0..1023
  for (int rep = 0; rep < K0_REP; ++rep) {
    REP_FENCE();
    const float4* wr = reinterpret_cast<const float4*>(Wq + (size_t)j * DMODEL) + l * 4;
    const float4 w0 = wr[0], w1 = wr[1], w2 = wr[2], w3 = wr[3];
    for (int b = bq * 16; b < bq * 16 + 16; ++b) {
      const float4* qr = reinterpret_cast<const float4*>(query + (size_t)b * DMODEL) + l * 4;
      float4 q0 = qr[0], q1 = qr[1], q2 = qr[2], q3 = qr[3];
      float s = 0.f;
      DOT4_ACC(s, w0, q0); DOT4_ACC(s, w1, q1); DOT4_ACC(s, w2, q2); DOT4_ACC(s, w3, q3);
      s = wred_sum(s);
      if (l == 0) qp[(size_t)b * DMODEL + j] = s;
    }
  }
}

// K1 (R13 body, repped): qt[b][h][m] = sum_d qp[b][h*64+d] * Wk[h*64+d][m].
__global__ __launch_bounds__(256) void k1_qt(const float* __restrict__ qp,
                                             const float* __restrict__ Wk,
                                             float* __restrict__ qt) {
  __shared__ __align__(16) float qpl[2][HD];
  const int h = blockIdx.x & 15;
  const int b0 = (blockIdx.x >> 4) * 2;
  const int tid = threadIdx.x;
  for (int rep = 0; rep < K1_REP; ++rep) {
    REP_FENCE();
    if (tid < 2 * HD) qpl[tid >> 6][tid & 63] =
        qp[(size_t)(b0 + (tid >> 6)) * DMODEL + h * HD + (tid & 63)];
    __syncthreads();
    const int m4 = tid * 4;
    float4 acc0 = make_float4(0.f, 0.f, 0.f, 0.f);
    float4 acc1 = make_float4(0.f, 0.f, 0.f, 0.f);
    const float* wbase = Wk + (size_t)(h * HD) * DMODEL + m4;
    for (int d = 0; d < HD; d += 4) {
      float4 wk0 = *reinterpret_cast<const float4*>(wbase + (size_t)(d + 0) * DMODEL);
      float4 wk1 = *reinterpret_cast<const float4*>(wbase + (size_t)(d + 1) * DMODEL);
      float4 wk2 = *reinterpret_cast<const float4*>(wbase + (size_t)(d + 2) * DMODEL);
      float4 wk3 = *reinterpret_cast<const float4*>(wbase + (size_t)(d + 3) * DMODEL);
      float4 qa = *reinterpret_cast<const float4*>(&qpl[0][d]);
      float4 qb = *reinterpret_cast<const float4*>(&qpl[1][d]);
      FMA4_BCAST(acc0, qa, wk0, wk1, wk2, wk3);
      FMA4_BCAST(acc1, qb, wk0, wk1, wk2, wk3);
    }
    *reinterpret_cast<float4*>(qt + ((size_t)(b0 + 0) * NH + h) * DMODEL + m4) = acc0;
    *reinterpret_cast<float4*>(qt + ((size_t)(b0 + 1) * NH + h) * DMODEL + m4) = acc1;
    __syncthreads();
  }
}

// K2 (R13-identical, 1 rep): partial scores, 4x4 lane tile, counted vmcnt.
__global__ __launch_bounds__(256) void k2_scores(const float* __restrict__ keys,
                                                 const float* __restrict__ qt,
                                                 float* __restrict__ scp) {
  __shared__ __align__(16) float kb[2][64 * 64];  // 2 x 16 KB
  __shared__ __align__(16) float qb[2][NH * 64];  // 2 x 4 KB
  const int b  = blockIdx.x & 63;
  const int st = (blockIdx.x >> 6) & 15;  // 0..15
  const int mh = blockIdx.x >> 10;        // 0..1
  const int tid = threadIdx.x, w = tid >> 6, l = tid & 63;
  const int hg = l & 3;
  const int rg = (l >> 2) & 3;
  const int hq = l >> 4;
  const int s0 = st * 64;
  const size_t rowstride = (size_t)NB * DMODEL;
  const float* kbase = keys + ((size_t)s0 * NB + b) * DMODEL + mh * 512;
  const float* qbase = qt + (size_t)b * NH * DMODEL + mh * 512;
  const int srow4 = l >> 4;
  const int sslot = l & 15;

#define K2_STAGE(buf_, ch_) do {                                               \
    _Pragma("unroll")                                                          \
    for (int i_ = 0; i_ < 4; ++i_) {                                           \
      const int r_ = w * 16 + i_ * 4 + srow4;                                  \
      gload16(kbase + (size_t)r_ * rowstride + (ch_) * 64 +                    \
                  ((sslot ^ (r_ & 7)) << 2),                                   \
              &kb[buf_][(w * 16 + i_ * 4) * 64]);                              \
    }                                                                          \
    gload16(qbase + (size_t)(w * 4 + srow4) * DMODEL + (ch_) * 64 +            \
                ((sslot ^ (w << 2)) << 2),                                     \
            &qb[buf_][w * 4 * 64]);                                            \
  } while (0)

  float acc[4][4];
#pragma unroll
  for (int r = 0; r < 4; ++r)
#pragma unroll
    for (int h = 0; h < 4; ++h) acc[r][h] = 0.f;

  K2_STAGE(0, 0);
  for (int ch = 0; ch < 8; ++ch) {
    const int buf = ch & 1;
    if (ch + 1 < 8) {
      K2_STAGE(buf ^ 1, ch + 1);
      VMCNT_WAIT(5);
    } else {
      VMCNT_WAIT(0);
    }
    BAR();
#pragma unroll
    for (int j = 0; j < 4; ++j) {
      float4 kv[4], qv[4];
#pragma unroll
      for (int r = 0; r < 4; ++r) {
        const int row = w * 16 + rg * 4 + r;
        kv[r] = *reinterpret_cast<const float4*>(
            &kb[buf][row * 64 + (((hg + 4 * j) ^ (row & 7)) << 2)]);
      }
#pragma unroll
      for (int h = 0; h < 4; ++h) {
        const int hh = hq * 4 + h;
        qv[h] = *reinterpret_cast<const float4*>(
            &qb[buf][hh * 64 + (((hg + 4 * j) ^ (hq << 2)) << 2)]);
      }
#pragma unroll
      for (int r = 0; r < 4; ++r)
#pragma unroll
        for (int h = 0; h < 4; ++h)
          DOT4_ACC(acc[r][h], kv[r], qv[h]);
    }
    BAR();
  }
#undef K2_STAGE
#pragma unroll
  for (int r = 0; r < 4; ++r)
#pragma unroll
    for (int h = 0; h < 4; ++h) {
      acc[r][h] += __shfl_xor(acc[r][h], 1, 64);
      acc[r][h] += __shfl_xor(acc[r][h], 2, 64);
    }
  const float scale = 0.125f;
  float* plane = scp + (size_t)mh * NB * NH * SLEN;
  float* orow = plane + ((size_t)b * NH + hq * 4 + hg) * SLEN + s0 + w * 16 + rg * 4;
#pragma unroll
  for (int r = 0; r < 4; ++r) {
    float v = hg == 0 ? acc[r][0] : hg == 1 ? acc[r][1]
            : hg == 2 ? acc[r][2] : acc[r][3];
    orow[r] = v * scale;
  }
}

// K_SM (repped, OUT-OF-PLACE): attn = softmax(sc0+sc1) along s.
__global__ __launch_bounds__(256) void k_sm(const float* __restrict__ sc0,
                                            const float* __restrict__ sc1,
                                            float* __restrict__ attn) {
  __shared__ float red[8];
  const int tid = threadIdx.x, w = tid >> 6, l = tid & 63;
  const float* p0 = sc0 + (size_t)blockIdx.x * SLEN;
  const float* p1 = sc1 + (size_t)blockIdx.x * SLEN;
  float* po = attn + (size_t)blockIdx.x * SLEN;
  for (int rep = 0; rep < KSM_REP; ++rep) {
    REP_FENCE();
    float4 xa = reinterpret_cast<const float4*>(p0)[tid];
    float4 xb = reinterpret_cast<const float4*>(p1)[tid];
    float4 x = make_float4(xa.x + xb.x, xa.y + xb.y, xa.z + xb.z, xa.w + xb.w);
    float mx = fmaxf(fmaxf(x.x, x.y), fmaxf(x.z, x.w));
#pragma unroll
    for (int off = 32; off; off >>= 1) mx = fmaxf(mx, __shfl_xor(mx, off, 64));
    if (l == 0) red[w] = mx;
    __syncthreads();
    mx = fmaxf(fmaxf(red[0], red[1]), fmaxf(red[2], red[3]));
    float4 e;
    e.x = __expf(x.x - mx); e.y = __expf(x.y - mx);
    e.z = __expf(x.z - mx); e.w = __expf(x.w - mx);
    float sum = e.x + e.y + e.z + e.w;
    sum = wred_sum(sum);
    if (l == 0) red[4 + w] = sum;
    __syncthreads();
    sum = red[4] + red[5] + red[6] + red[7];
    const float inv = 1.f / sum;
    e.x *= inv; e.y *= inv; e.z *= inv; e.w *= inv;
    reinterpret_cast<float4*>(po)[tid] = e;
    __syncthreads();
  }
}

// K3 (R13 body, repped): partial c[ch][b][h][m] = sum_{s in chunk} attn*values.
template <int NCH>
__global__ __launch_bounds__(256) void k3_cpart(const float* __restrict__ values,
                                                const float* __restrict__ attn,
                                                float* __restrict__ cp) {
  constexpr int SC = SLEN / NCH;
  __shared__ __align__(16) float vb[2][4][DMODEL];  // 32 KB
  __shared__ __align__(16) float al[NH][SC];
  const int b = blockIdx.x & 63;
  const int ch = blockIdx.x >> 6;
  const int s0 = ch * SC;
  const int tid = threadIdx.x, w = tid >> 6, l = tid & 63;
  const int m4 = tid * 4;
  const size_t rowstride = (size_t)NB * DMODEL;
  const float* vbase = values + ((size_t)s0 * NB + b) * DMODEL;

#define K3_STAGE(buf_, g_) do {                                               \
    const float* rg_ = vbase + (size_t)((g_) * 4 + w) * rowstride;            \
    _Pragma("unroll")                                                         \
    for (int j_ = 0; j_ < 4; ++j_)                                            \
      gload16(rg_ + j_ * 256 + l * 4, &vb[buf_][w][j_ * 256]);                \
  } while (0)

  for (int rep = 0; rep < K3_REP; ++rep) {
    REP_FENCE();
    for (int f = tid; f < NH * (SC / 4); f += 256) {
      int hh = f / (SC / 4), c4 = (f % (SC / 4)) * 4;
      *reinterpret_cast<float4*>(&al[hh][c4]) = *reinterpret_cast<const float4*>(
          attn + ((size_t)b * NH + hh) * SLEN + s0 + c4);
    }
    float4 acc[NH];
#pragma unroll
    for (int i = 0; i < NH; ++i) acc[i] = make_float4(0.f, 0.f, 0.f, 0.f);

    K3_STAGE(0, 0);
    __syncthreads();  // covers al fill + prologue stage
    for (int g = 0; g < SC / 4; ++g) {
      const int buf = g & 1;
      if (g + 1 < SC / 4) {
        K3_STAGE(buf ^ 1, g + 1);
        VMCNT_WAIT(4);
      } else {
        VMCNT_WAIT(0);
      }
      BAR();
      float4 v0 = *reinterpret_cast<const float4*>(&vb[buf][0][m4]);
      float4 v1 = *reinterpret_cast<const float4*>(&vb[buf][1][m4]);
      float4 v2 = *reinterpret_cast<const float4*>(&vb[buf][2][m4]);
      float4 v3 = *reinterpret_cast<const float4*>(&vb[buf][3][m4]);
#pragma unroll
      for (int hh = 0; hh < NH; ++hh) {
        float4 av = *reinterpret_cast<const float4*>(&al[hh][g * 4]);
        FMA4_BCAST(acc[hh], av, v0, v1, v2, v3);
      }
      BAR();
    }
#pragma unroll
    for (int hh = 0; hh < NH; ++hh)
      *reinterpret_cast<float4*>(cp + (((size_t)ch * NB + b) * NH + hh) * DMODEL + m4) = acc[hh];
    __syncthreads();
  }
#undef K3_STAGE
}

// K4 (repped): out[b][h*64+d] = sum_m Wk[h*64+d][m] * (sum_ch cp[...]).
template <int NCH>
__global__ __launch_bounds__(256) void k4_out(const float* __restrict__ cp,
                                              const float* __restrict__ Wk,
                                              float* __restrict__ out) {
  __shared__ __align__(16) float cl[4 * DMODEL];
  const int h = blockIdx.x & 15;
  const int b0 = (blockIdx.x >> 4) * 4;
  const int tid = threadIdx.x, w = tid >> 6, l = tid & 63;
  for (int rep = 0; rep < K4_REP; ++rep) {
    REP_FENCE();
    for (int f = tid; f < 4 * DMODEL / 4; f += 256) {
      int bi = f >> 8, m4 = (f & 255) * 4;
      float4 s = make_float4(0.f, 0.f, 0.f, 0.f);
#pragma unroll
      for (int ch = 0; ch < NCH; ++ch) {
        float4 t = *reinterpret_cast<const float4*>(
            cp + (((size_t)ch * NB + b0 + bi) * NH + h) * DMODEL + m4);
        s.x += t.x; s.y += t.y; s.z += t.z; s.w += t.w;
      }
      *reinterpret_cast<float4*>(&cl[bi * DMODEL + m4]) = s;
    }
    __syncthreads();
    float4 c[4][4];
#pragma unroll
    for (int bi = 0; bi < 4; ++bi)
#pragma unroll
      for (int k = 0; k < 4; ++k)
        c[bi][k] = *reinterpret_cast<const float4*>(&cl[bi * DMODEL + l * 16 + k * 4]);
    for (int jj = 0; jj < 16; ++jj) {
      const int d = w * 16 + jj;
      const float4* wr = reinterpret_cast<const float4*>(Wk + (size_t)(h * HD + d) * DMODEL) + l * 4;
      const float4 w0 = wr[0], w1 = wr[1], w2 = wr[2], w3 = wr[3];
#pragma unroll
      for (int bi = 0; bi < 4; ++bi) {
        float s = 0.f;
        DOT4_ACC(s, w0, c[bi][0]); DOT4_ACC(s, w1, c[bi][1]);
        DOT4_ACC(s, w2, c[bi][2]); DOT4_ACC(s, w3, c[bi][3]);
        s = wred_sum(s);
        if (l == 0) out[(size_t)(b0 + bi) * (NH * HD) + h * HD + d] = s;
      }
    }
    __syncthreads();
  }
}

extern "C" void kernel_launch(void* const* d_in, const int* in_sizes, int n_in,
                              void* d_out, int out_size, void* d_ws, size_t ws_size,
                              hipStream_t stream) {
  const float* query  = (const float*)d_in[0];
  const float* keys   = (const float*)d_in[1];
  const float* values = (const float*)d_in[2];
  const float* Wq     = (const float*)d_in[3];
  const float* Wk     = (const float*)d_in[4];
  float* out = (float*)d_out;

  float* W    = (float*)d_ws;
  float* qp   = W;                                   // 64*1024
  float* qt   = qp + (size_t)NB * DMODEL;            // 64*16*1024
  float* sc0  = qt + (size_t)NB * NH * DMODEL;       // partial m-half 0
  float* sc1  = sc0 + (size_t)NB * NH * SLEN;        // partial m-half 1
  float* attn = sc1 + (size_t)NB * NH * SLEN;        // softmax output
  float* cp   = attn + (size_t)NB * NH * SLEN;       // NCH*64*16*1024

  const size_t base_floats = (size_t)NB * DMODEL + (size_t)NB * NH * DMODEL
                           + 3 * (size_t)NB * NH * SLEN;

  k0_qp<<<1024, 256, 0, stream>>>(query, Wq, qp);
  k1_qt<<<512, 256, 0, stream>>>(qp, Wk, qt);
  k2_scores<<<2048, 256, 0, stream>>>(keys, qt, sc0);  // writes sc0/sc1 planes
  k_sm<<<NB * NH, 256, 0, stream>>>(sc0, sc1, attn);

  const size_t chunk_floats = (size_t)NB * NH * DMODEL;
  if (ws_size >= (base_floats + 16 * chunk_floats) * sizeof(float)) {
    k3_cpart<16><<<16 * NB, 256, 0, stream>>>(values, attn, cp);
    k4_out<16><<<NH * (NB / 4), 256, 0, stream>>>(cp, Wk, out);
  } else if (ws_size >= (base_floats + 8 * chunk_floats) * sizeof(float)) {
    k3_cpart<8><<<8 * NB, 256, 0, stream>>>(values, attn, cp);
    k4_out<8><<<NH * (NB / 4), 256, 0, stream>>>(cp, Wk, out);
  } else {
    k3_cpart<4><<<4 * NB, 256, 0, stream>>>(values, attn, cp);
    k4_out<4><<<NH * (NB / 4), 256, 0, stream>>>(cp, Wk, out);
  }
}

// Round 15
// 208.915 us; speedup vs baseline: 5.4632x; 5.4632x over previous
//
#include <hip/hip_runtime.h>
#include <cstddef>
#include <cstdint>

#define NH 16
#define HD 64
#define SLEN 1024
#define NB 64
#define DMODEL 1024

#define DOT4_ACC(acc, k, q) \
  acc = fmaf((k).x, (q).x, fmaf((k).y, (q).y, fmaf((k).z, (q).z, fmaf((k).w, (q).w, (acc)))))

#define FMA4_BCAST(accv, qv, w0_, w1_, w2_, w3_) do { \
  (accv).x = fmaf((qv).x, (w0_).x, fmaf((qv).y, (w1_).x, fmaf((qv).z, (w2_).x, fmaf((qv).w, (w3_).x, (accv).x)))); \
  (accv).y = fmaf((qv).x, (w0_).y, fmaf((qv).y, (w1_).y, fmaf((qv).z, (w2_).y, fmaf((qv).w, (w3_).y, (accv).y)))); \
  (accv).z = fmaf((qv).x, (w0_).z, fmaf((qv).y, (w1_).z, fmaf((qv).z, (w2_).z, fmaf((qv).w, (w3_).z, (accv).z)))); \
  (accv).w = fmaf((qv).x, (w0_).w, fmaf((qv).y, (w1_).w, fmaf((qv).z, (w2_).w, fmaf((qv).w, (w3_).w, (accv).w)))); \
} while (0)

#define VMCNT_WAIT(n) asm volatile("s_waitcnt vmcnt(" #n ")" ::: "memory")
#define BAR() asm volatile("s_barrier" ::: "memory")

__device__ __forceinline__ float wred_sum(float v) {
#pragma unroll
  for (int off = 32; off; off >>= 1) v += __shfl_xor(v, off, 64);
  return v;
}

__device__ __forceinline__ void gload16(const float* g, float* lds_base) {
  __builtin_amdgcn_global_load_lds(
      (const __attribute__((address_space(1))) void*)g,
      (__attribute__((address_space(3))) void*)lds_base, 16, 0, 0);
}

// K0 v3: qp[b][j] = sum_c query[b][c] * Wq[j][c]. Grid 1024 = jq(256) x bq(4).
// BATCHED: all 16 per-b partial dots first (loads pipeline, 256-FMA ILP),
// THEN 16 interleaved shuffle-reduce chains (was: serial chain per b ->
// 16.2us measured in R14; dependent-latency-bound at VALUBusy 19%).
__global__ __launch_bounds__(256) void k0_qp(const float* __restrict__ query,
                                             const float* __restrict__ Wq,
                                             float* __restrict__ qp) {
  const int tid = threadIdx.x;
  const int w = tid >> 6, l = tid & 63;
  const int jq = blockIdx.x & 255;
  const int bq = blockIdx.x >> 8;      // 0..3
  const int j = jq * 4 + w;            // 0..1023
  const float4* wr = reinterpret_cast<const float4*>(Wq + (size_t)j * DMODEL) + l * 4;
  const float4 w0 = wr[0], w1 = wr[1], w2 = wr[2], w3 = wr[3];
  float acc[16];
#pragma unroll
  for (int bi = 0; bi < 16; ++bi) {
    const float4* qr = reinterpret_cast<const float4*>(
        query + (size_t)(bq * 16 + bi) * DMODEL) + l * 4;
    float4 q0 = qr[0], q1 = qr[1], q2 = qr[2], q3 = qr[3];
    float s = 0.f;
    DOT4_ACC(s, w0, q0); DOT4_ACC(s, w1, q1); DOT4_ACC(s, w2, q2); DOT4_ACC(s, w3, q3);
    acc[bi] = s;
  }
#pragma unroll
  for (int off = 32; off; off >>= 1) {
#pragma unroll
    for (int bi = 0; bi < 16; ++bi) acc[bi] += __shfl_xor(acc[bi], off, 64);
  }
  if (l == 0) {
#pragma unroll
    for (int bi = 0; bi < 16; ++bi)
      qp[(size_t)(bq * 16 + bi) * DMODEL + j] = acc[bi];
  }
}

// K1 (R13-identical): qt[b][h][m] = sum_d qp[b][h*64+d] * Wk[h*64+d][m].
__global__ __launch_bounds__(256) void k1_qt(const float* __restrict__ qp,
                                             const float* __restrict__ Wk,
                                             float* __restrict__ qt) {
  __shared__ __align__(16) float qpl[2][HD];
  const int h = blockIdx.x & 15;
  const int b0 = (blockIdx.x >> 4) * 2;
  const int tid = threadIdx.x;
  if (tid < 2 * HD) qpl[tid >> 6][tid & 63] =
      qp[(size_t)(b0 + (tid >> 6)) * DMODEL + h * HD + (tid & 63)];
  __syncthreads();
  const int m4 = tid * 4;
  float4 acc0 = make_float4(0.f, 0.f, 0.f, 0.f);
  float4 acc1 = make_float4(0.f, 0.f, 0.f, 0.f);
  const float* wbase = Wk + (size_t)(h * HD) * DMODEL + m4;
  for (int d = 0; d < HD; d += 4) {
    float4 wk0 = *reinterpret_cast<const float4*>(wbase + (size_t)(d + 0) * DMODEL);
    float4 wk1 = *reinterpret_cast<const float4*>(wbase + (size_t)(d + 1) * DMODEL);
    float4 wk2 = *reinterpret_cast<const float4*>(wbase + (size_t)(d + 2) * DMODEL);
    float4 wk3 = *reinterpret_cast<const float4*>(wbase + (size_t)(d + 3) * DMODEL);
    float4 qa = *reinterpret_cast<const float4*>(&qpl[0][d]);
    float4 qb = *reinterpret_cast<const float4*>(&qpl[1][d]);
    FMA4_BCAST(acc0, qa, wk0, wk1, wk2, wk3);
    FMA4_BCAST(acc1, qb, wk0, wk1, wk2, wk3);
  }
  *reinterpret_cast<float4*>(qt + ((size_t)(b0 + 0) * NH + h) * DMODEL + m4) = acc0;
  *reinterpret_cast<float4*>(qt + ((size_t)(b0 + 1) * NH + h) * DMODEL + m4) = acc1;
}

// K2 (R13-identical): partial scores, 4x4 lane tile, counted vmcnt.
__global__ __launch_bounds__(256) void k2_scores(const float* __restrict__ keys,
                                                 const float* __restrict__ qt,
                                                 float* __restrict__ scp) {
  __shared__ __align__(16) float kb[2][64 * 64];  // 2 x 16 KB
  __shared__ __align__(16) float qb[2][NH * 64];  // 2 x 4 KB
  const int b  = blockIdx.x & 63;
  const int st = (blockIdx.x >> 6) & 15;  // 0..15
  const int mh = blockIdx.x >> 10;        // 0..1
  const int tid = threadIdx.x, w = tid >> 6, l = tid & 63;
  const int hg = l & 3;
  const int rg = (l >> 2) & 3;
  const int hq = l >> 4;
  const int s0 = st * 64;
  const size_t rowstride = (size_t)NB * DMODEL;
  const float* kbase = keys + ((size_t)s0 * NB + b) * DMODEL + mh * 512;
  const float* qbase = qt + (size_t)b * NH * DMODEL + mh * 512;
  const int srow4 = l >> 4;
  const int sslot = l & 15;

#define K2_STAGE(buf_, ch_) do {                                               \
    _Pragma("unroll")                                                          \
    for (int i_ = 0; i_ < 4; ++i_) {                                           \
      const int r_ = w * 16 + i_ * 4 + srow4;                                  \
      gload16(kbase + (size_t)r_ * rowstride + (ch_) * 64 +                    \
                  ((sslot ^ (r_ & 7)) << 2),                                   \
              &kb[buf_][(w * 16 + i_ * 4) * 64]);                              \
    }                                                                          \
    gload16(qbase + (size_t)(w * 4 + srow4) * DMODEL + (ch_) * 64 +            \
                ((sslot ^ (w << 2)) << 2),                                     \
            &qb[buf_][w * 4 * 64]);                                            \
  } while (0)

  float acc[4][4];
#pragma unroll
  for (int r = 0; r < 4; ++r)
#pragma unroll
    for (int h = 0; h < 4; ++h) acc[r][h] = 0.f;

  K2_STAGE(0, 0);
  for (int ch = 0; ch < 8; ++ch) {
    const int buf = ch & 1;
    if (ch + 1 < 8) {
      K2_STAGE(buf ^ 1, ch + 1);
      VMCNT_WAIT(5);
    } else {
      VMCNT_WAIT(0);
    }
    BAR();
#pragma unroll
    for (int j = 0; j < 4; ++j) {
      float4 kv[4], qv[4];
#pragma unroll
      for (int r = 0; r < 4; ++r) {
        const int row = w * 16 + rg * 4 + r;
        kv[r] = *reinterpret_cast<const float4*>(
            &kb[buf][row * 64 + (((hg + 4 * j) ^ (row & 7)) << 2)]);
      }
#pragma unroll
      for (int h = 0; h < 4; ++h) {
        const int hh = hq * 4 + h;
        qv[h] = *reinterpret_cast<const float4*>(
            &qb[buf][hh * 64 + (((hg + 4 * j) ^ (hq << 2)) << 2)]);
      }
#pragma unroll
      for (int r = 0; r < 4; ++r)
#pragma unroll
        for (int h = 0; h < 4; ++h)
          DOT4_ACC(acc[r][h], kv[r], qv[h]);
    }
    BAR();
  }
#undef K2_STAGE
#pragma unroll
  for (int r = 0; r < 4; ++r)
#pragma unroll
    for (int h = 0; h < 4; ++h) {
      acc[r][h] += __shfl_xor(acc[r][h], 1, 64);
      acc[r][h] += __shfl_xor(acc[r][h], 2, 64);
    }
  const float scale = 0.125f;
  float* plane = scp + (size_t)mh * NB * NH * SLEN;
  float* orow = plane + ((size_t)b * NH + hq * 4 + hg) * SLEN + s0 + w * 16 + rg * 4;
#pragma unroll
  for (int r = 0; r < 4; ++r) {
    float v = hg == 0 ? acc[r][0] : hg == 1 ? acc[r][1]
            : hg == 2 ? acc[r][2] : acc[r][3];
    orow[r] = v * scale;
  }
}

// K_SM (R13-identical): sums the two partial planes, softmax, writes plane0.
__global__ __launch_bounds__(256) void k_sm(float* __restrict__ sc0,
                                            const float* __restrict__ sc1) {
  __shared__ float red[8];
  const int tid = threadIdx.x, w = tid >> 6, l = tid & 63;
  float* p0 = sc0 + (size_t)blockIdx.x * SLEN;
  const float* p1 = sc1 + (size_t)blockIdx.x * SLEN;
  float4 xa = reinterpret_cast<const float4*>(p0)[tid];
  float4 xb = reinterpret_cast<const float4*>(p1)[tid];
  float4 x = make_float4(xa.x + xb.x, xa.y + xb.y, xa.z + xb.z, xa.w + xb.w);
  float mx = fmaxf(fmaxf(x.x, x.y), fmaxf(x.z, x.w));
#pragma unroll
  for (int off = 32; off; off >>= 1) mx = fmaxf(mx, __shfl_xor(mx, off, 64));
  if (l == 0) red[w] = mx;
  __syncthreads();
  mx = fmaxf(fmaxf(red[0], red[1]), fmaxf(red[2], red[3]));
  float4 e;
  e.x = __expf(x.x - mx); e.y = __expf(x.y - mx);
  e.z = __expf(x.z - mx); e.w = __expf(x.w - mx);
  float sum = e.x + e.y + e.z + e.w;
  sum = wred_sum(sum);
  if (l == 0) red[4 + w] = sum;
  __syncthreads();
  sum = red[4] + red[5] + red[6] + red[7];
  const float inv = 1.f / sum;
  e.x *= inv; e.y *= inv; e.z *= inv; e.w *= inv;
  reinterpret_cast<float4*>(p0)[tid] = e;
}

// K3 (R13-identical): partial c[ch][b][h][m] = sum_{s in chunk} attn*values.
template <int NCH>
__global__ __launch_bounds__(256) void k3_cpart(const float* __restrict__ values,
                                                const float* __restrict__ attn,
                                                float* __restrict__ cp) {
  constexpr int SC = SLEN / NCH;
  __shared__ __align__(16) float vb[2][4][DMODEL];  // 32 KB
  __shared__ __align__(16) float al[NH][SC];
  const int b = blockIdx.x & 63;
  const int ch = blockIdx.x >> 6;
  const int s0 = ch * SC;
  const int tid = threadIdx.x, w = tid >> 6, l = tid & 63;
  for (int f = tid; f < NH * (SC / 4); f += 256) {
    int hh = f / (SC / 4), c4 = (f % (SC / 4)) * 4;
    *reinterpret_cast<float4*>(&al[hh][c4]) = *reinterpret_cast<const float4*>(
        attn + ((size_t)b * NH + hh) * SLEN + s0 + c4);
  }
  const int m4 = tid * 4;
  float4 acc[NH];
#pragma unroll
  for (int i = 0; i < NH; ++i) acc[i] = make_float4(0.f, 0.f, 0.f, 0.f);
  const size_t rowstride = (size_t)NB * DMODEL;
  const float* vbase = values + ((size_t)s0 * NB + b) * DMODEL;

#define K3_STAGE(buf_, g_) do {                                               \
    const float* rg_ = vbase + (size_t)((g_) * 4 + w) * rowstride;            \
    _Pragma("unroll")                                                         \
    for (int j_ = 0; j_ < 4; ++j_)                                            \
      gload16(rg_ + j_ * 256 + l * 4, &vb[buf_][w][j_ * 256]);                \
  } while (0)

  K3_STAGE(0, 0);
  __syncthreads();  // covers al fill + prologue stage
  for (int g = 0; g < SC / 4; ++g) {
    const int buf = g & 1;
    if (g + 1 < SC / 4) {
      K3_STAGE(buf ^ 1, g + 1);
      VMCNT_WAIT(4);
    } else {
      VMCNT_WAIT(0);
    }
    BAR();
    float4 v0 = *reinterpret_cast<const float4*>(&vb[buf][0][m4]);
    float4 v1 = *reinterpret_cast<const float4*>(&vb[buf][1][m4]);
    float4 v2 = *reinterpret_cast<const float4*>(&vb[buf][2][m4]);
    float4 v3 = *reinterpret_cast<const float4*>(&vb[buf][3][m4]);
#pragma unroll
    for (int hh = 0; hh < NH; ++hh) {
      float4 av = *reinterpret_cast<const float4*>(&al[hh][g * 4]);  // broadcast
      FMA4_BCAST(acc[hh], av, v0, v1, v2, v3);
    }
    BAR();
  }
#undef K3_STAGE
#pragma unroll
  for (int hh = 0; hh < NH; ++hh)
    *reinterpret_cast<float4*>(cp + (((size_t)ch * NB + b) * NH + hh) * DMODEL + m4) = acc[hh];
}

// K4 v2: out[b][h*64+d] = sum_m Wk[h*64+d][m] * (sum_ch cp[ch][b][h][m]).
// Grid 512 = h(16) x b-PAIR(32): 2x occupancy vs R13's 256 (1 blk/CU measured
// ~20-25us), and 32 (not 64) shuffle chains per wave.
template <int NCH>
__global__ __launch_bounds__(256) void k4_out(const float* __restrict__ cp,
                                              const float* __restrict__ Wk,
                                              float* __restrict__ out) {
  __shared__ __align__(16) float cl[2 * DMODEL];
  const int h = blockIdx.x & 15;
  const int b0 = (blockIdx.x >> 4) * 2;
  const int tid = threadIdx.x, w = tid >> 6, l = tid & 63;
  for (int f = tid; f < 2 * DMODEL / 4; f += 256) {
    int bi = f >> 8, m4 = (f & 255) * 4;
    float4 s = make_float4(0.f, 0.f, 0.f, 0.f);
#pragma unroll
    for (int ch = 0; ch < NCH; ++ch) {
      float4 t = *reinterpret_cast<const float4*>(
          cp + (((size_t)ch * NB + b0 + bi) * NH + h) * DMODEL + m4);
      s.x += t.x; s.y += t.y; s.z += t.z; s.w += t.w;
    }
    *reinterpret_cast<float4*>(&cl[bi * DMODEL + m4]) = s;
  }
  __syncthreads();
  float4 c[2][4];
#pragma unroll
  for (int bi = 0; bi < 2; ++bi)
#pragma unroll
    for (int k = 0; k < 4; ++k)
      c[bi][k] = *reinterpret_cast<const float4*>(&cl[bi * DMODEL + l * 16 + k * 4]);
  for (int jj = 0; jj < 16; ++jj) {
    const int d = w * 16 + jj;
    const float4* wr = reinterpret_cast<const float4*>(Wk + (size_t)(h * HD + d) * DMODEL) + l * 4;
    const float4 w0 = wr[0], w1 = wr[1], w2 = wr[2], w3 = wr[3];
#pragma unroll
    for (int bi = 0; bi < 2; ++bi) {
      float s = 0.f;
      DOT4_ACC(s, w0, c[bi][0]); DOT4_ACC(s, w1, c[bi][1]);
      DOT4_ACC(s, w2, c[bi][2]); DOT4_ACC(s, w3, c[bi][3]);
      s = wred_sum(s);
      if (l == 0) out[(size_t)(b0 + bi) * (NH * HD) + h * HD + d] = s;
    }
  }
}

extern "C" void kernel_launch(void* const* d_in, const int* in_sizes, int n_in,
                              void* d_out, int out_size, void* d_ws, size_t ws_size,
                              hipStream_t stream) {
  const float* query  = (const float*)d_in[0];
  const float* keys   = (const float*)d_in[1];
  const float* values = (const float*)d_in[2];
  const float* Wq     = (const float*)d_in[3];
  const float* Wk     = (const float*)d_in[4];
  float* out = (float*)d_out;

  float* W   = (float*)d_ws;
  float* qp  = W;                                   // 64*1024
  float* qt  = qp + (size_t)NB * DMODEL;            // 64*16*1024
  float* sc0 = qt + (size_t)NB * NH * DMODEL;       // partial m-half 0 -> attn
  float* sc1 = sc0 + (size_t)NB * NH * SLEN;        // partial m-half 1
  float* cp  = sc1 + (size_t)NB * NH * SLEN;        // NCH*64*16*1024

  const size_t base_floats = (size_t)NB * DMODEL + (size_t)NB * NH * DMODEL
                           + 2 * (size_t)NB * NH * SLEN;

  k0_qp<<<1024, 256, 0, stream>>>(query, Wq, qp);
  k1_qt<<<512, 256, 0, stream>>>(qp, Wk, qt);
  k2_scores<<<2048, 256, 0, stream>>>(keys, qt, sc0);  // writes sc0 (mh=0) / sc1 (mh=1)
  k_sm<<<NB * NH, 256, 0, stream>>>(sc0, sc1);

  const size_t chunk_floats = (size_t)NB * NH * DMODEL;
  if (ws_size >= (base_floats + 16 * chunk_floats) * sizeof(float)) {
    k3_cpart<16><<<16 * NB, 256, 0, stream>>>(values, sc0, cp);
    k4_out<16><<<NH * (NB / 2), 256, 0, stream>>>(cp, Wk, out);
  } else if (ws_size >= (base_floats + 8 * chunk_floats) * sizeof(float)) {
    k3_cpart<8><<<8 * NB, 256, 0, stream>>>(values, sc0, cp);
    k4_out<8><<<NH * (NB / 2), 256, 0, stream>>>(cp, Wk, out);
  } else {
    k3_cpart<4><<<4 * NB, 256, 0, stream>>>(values, sc0, cp);
    k4_out<4><<<NH * (NB / 2), 256, 0, stream>>>(cp, Wk, out);
  }
}

// Round 16
// 207.401 us; speedup vs baseline: 5.5031x; 1.0073x over previous
//
#include <hip/hip_runtime.h>
#include <cstddef>
#include <cstdint>

#define NH 16
#define HD 64
#define SLEN 1024
#define NB 64
#define DMODEL 1024

#define DOT4_ACC(acc, k, q) \
  acc = fmaf((k).x, (q).x, fmaf((k).y, (q).y, fmaf((k).z, (q).z, fmaf((k).w, (q).w, (acc)))))

#define FMA4_BCAST(accv, qv, w0_, w1_, w2_, w3_) do { \
  (accv).x = fmaf((qv).x, (w0_).x, fmaf((qv).y, (w1_).x, fmaf((qv).z, (w2_).x, fmaf((qv).w, (w3_).x, (accv).x)))); \
  (accv).y = fmaf((qv).x, (w0_).y, fmaf((qv).y, (w1_).y, fmaf((qv).z, (w2_).y, fmaf((qv).w, (w3_).y, (accv).y)))); \
  (accv).z = fmaf((qv).x, (w0_).z, fmaf((qv).y, (w1_).z, fmaf((qv).z, (w2_).z, fmaf((qv).w, (w3_).z, (accv).z)))); \
  (accv).w = fmaf((qv).x, (w0_).w, fmaf((qv).y, (w1_).w, fmaf((qv).z, (w2_).w, fmaf((qv).w, (w3_).w, (accv).w)))); \
} while (0)

#define VMCNT_WAIT(n) asm volatile("s_waitcnt vmcnt(" #n ")" ::: "memory")
#define BAR() asm volatile("s_barrier" ::: "memory")

__device__ __forceinline__ float wred_sum(float v) {
#pragma unroll
  for (int off = 32; off; off >>= 1) v += __shfl_xor(v, off, 64);
  return v;
}

__device__ __forceinline__ void gload16(const float* g, float* lds_base) {
  __builtin_amdgcn_global_load_lds(
      (const __attribute__((address_space(1))) void*)g,
      (__attribute__((address_space(3))) void*)lds_base, 16, 0, 0);
}

// K0 v3 (R15-identical): qp[b][j] = sum_c query[b][c] * Wq[j][c].
__global__ __launch_bounds__(256) void k0_qp(const float* __restrict__ query,
                                             const float* __restrict__ Wq,
                                             float* __restrict__ qp) {
  const int tid = threadIdx.x;
  const int w = tid >> 6, l = tid & 63;
  const int jq = blockIdx.x & 255;
  const int bq = blockIdx.x >> 8;      // 0..3
  const int j = jq * 4 + w;            // 0..1023
  const float4* wr = reinterpret_cast<const float4*>(Wq + (size_t)j * DMODEL) + l * 4;
  const float4 w0 = wr[0], w1 = wr[1], w2 = wr[2], w3 = wr[3];
  float acc[16];
#pragma unroll
  for (int bi = 0; bi < 16; ++bi) {
    const float4* qr = reinterpret_cast<const float4*>(
        query + (size_t)(bq * 16 + bi) * DMODEL) + l * 4;
    float4 q0 = qr[0], q1 = qr[1], q2 = qr[2], q3 = qr[3];
    float s = 0.f;
    DOT4_ACC(s, w0, q0); DOT4_ACC(s, w1, q1); DOT4_ACC(s, w2, q2); DOT4_ACC(s, w3, q3);
    acc[bi] = s;
  }
#pragma unroll
  for (int off = 32; off; off >>= 1) {
#pragma unroll
    for (int bi = 0; bi < 16; ++bi) acc[bi] += __shfl_xor(acc[bi], off, 64);
  }
  if (l == 0) {
#pragma unroll
    for (int bi = 0; bi < 16; ++bi)
      qp[(size_t)(bq * 16 + bi) * DMODEL + j] = acc[bi];
  }
}

// K1 (R15-identical): qt[b][h][m] = sum_d qp[b][h*64+d] * Wk[h*64+d][m].
__global__ __launch_bounds__(256) void k1_qt(const float* __restrict__ qp,
                                             const float* __restrict__ Wk,
                                             float* __restrict__ qt) {
  __shared__ __align__(16) float qpl[2][HD];
  const int h = blockIdx.x & 15;
  const int b0 = (blockIdx.x >> 4) * 2;
  const int tid = threadIdx.x;
  if (tid < 2 * HD) qpl[tid >> 6][tid & 63] =
      qp[(size_t)(b0 + (tid >> 6)) * DMODEL + h * HD + (tid & 63)];
  __syncthreads();
  const int m4 = tid * 4;
  float4 acc0 = make_float4(0.f, 0.f, 0.f, 0.f);
  float4 acc1 = make_float4(0.f, 0.f, 0.f, 0.f);
  const float* wbase = Wk + (size_t)(h * HD) * DMODEL + m4;
  for (int d = 0; d < HD; d += 4) {
    float4 wk0 = *reinterpret_cast<const float4*>(wbase + (size_t)(d + 0) * DMODEL);
    float4 wk1 = *reinterpret_cast<const float4*>(wbase + (size_t)(d + 1) * DMODEL);
    float4 wk2 = *reinterpret_cast<const float4*>(wbase + (size_t)(d + 2) * DMODEL);
    float4 wk3 = *reinterpret_cast<const float4*>(wbase + (size_t)(d + 3) * DMODEL);
    float4 qa = *reinterpret_cast<const float4*>(&qpl[0][d]);
    float4 qb = *reinterpret_cast<const float4*>(&qpl[1][d]);
    FMA4_BCAST(acc0, qa, wk0, wk1, wk2, wk3);
    FMA4_BCAST(acc1, qb, wk0, wk1, wk2, wk3);
  }
  *reinterpret_cast<float4*>(qt + ((size_t)(b0 + 0) * NH + h) * DMODEL + m4) = acc0;
  *reinterpret_cast<float4*>(qt + ((size_t)(b0 + 1) * NH + h) * DMODEL + m4) = acc1;
}

// K2 v12: 8x8 lane tile -> 16 ds_read_b128 per 64 dot4 (half of v10's ratio;
// per-CU LDS time 41us -> ~20us, under the 37us HBM stream).
// Block = (b, st: 256-s tile, mh): grid 512 = exactly 2 blocks/CU.
// Chunk = 32 m-floats; kb 2x32KB + qb 2x2KB = 68KB -> 2 blocks/CU.
// Wave w stages AND computes rows w*64..+63. q staged by waves 0,1.
// Lane = (ms: m-stripe 0..3, rg: row-group 0..7, hq: head-half 0..1);
// lane tile = 8 rows x 8 heads. Swizzle slot^(row&7): row&7==r and hh&7==h
// make the read XOR compile-time. Counted vmcnt (9/8), raw barriers.
__global__ __launch_bounds__(256, 2) void k2_scores(const float* __restrict__ keys,
                                                    const float* __restrict__ qt,
                                                    float* __restrict__ scp) {
  __shared__ __align__(16) float kb[2][256 * 32];  // 2 x 32 KB
  __shared__ __align__(16) float qb[2][NH * 32];   // 2 x 2 KB
  const int b  = blockIdx.x & 63;
  const int st = (blockIdx.x >> 6) & 3;   // 0..3 (256-s tiles)
  const int mh = blockIdx.x >> 8;         // 0..1
  const int tid = threadIdx.x, w = tid >> 6, l = tid & 63;
  const int ms = l & 3;                   // m-stripe
  const int rg = (l >> 2) & 7;            // row-group (8 rows each)
  const int hq = l >> 5;                  // head-half (8 heads each)
  const int s0 = st * 256;
  const size_t rowstride = (size_t)NB * DMODEL;
  const float* kbase = keys + ((size_t)s0 * NB + b) * DMODEL + mh * 512;
  const float* qbase = qt + (size_t)b * NH * DMODEL + mh * 512;
  const int srow  = l >> 3;               // row within 8-row stage unit (=row&7)
  const int sslot = l & 7;                // 16B slot within 128B row-chunk

#define K2_STAGE(buf_, ch_) do {                                               \
    _Pragma("unroll")                                                          \
    for (int i_ = 0; i_ < 8; ++i_) {                                           \
      const int r_ = w * 64 + i_ * 8 + srow;                                   \
      gload16(kbase + (size_t)r_ * rowstride + (ch_) * 32 +                    \
                  ((sslot ^ srow) << 2),                                       \
              &kb[buf_][(w * 64 + i_ * 8) * 32]);                              \
    }                                                                          \
    if (w < 2)                                                                 \
      gload16(qbase + (size_t)(w * 8 + srow) * DMODEL + (ch_) * 32 +           \
                  ((sslot ^ srow) << 2),                                       \
              &qb[buf_][w * 8 * 32]);                                          \
  } while (0)

  float acc[8][8];  // [r][h]
#pragma unroll
  for (int r = 0; r < 8; ++r)
#pragma unroll
    for (int h = 0; h < 8; ++h) acc[r][h] = 0.f;

  K2_STAGE(0, 0);
  for (int ch = 0; ch < 16; ++ch) {
    const int buf = ch & 1;
    if (ch + 1 < 16) {
      K2_STAGE(buf ^ 1, ch + 1);  // issue next chunk's loads FIRST
      if (w < 2) { VMCNT_WAIT(9); } else { VMCNT_WAIT(8); }
    } else {
      VMCNT_WAIT(0);
    }
    BAR();                        // every wave's current-chunk loads landed
#pragma unroll
    for (int j = 0; j < 2; ++j) {
      const int c = j * 4 + ms;   // col4 index 0..7
      float4 kv[8], qv[8];
#pragma unroll
      for (int r = 0; r < 8; ++r) {
        const int row = w * 64 + rg * 8 + r;  // row&7 == r
        kv[r] = *reinterpret_cast<const float4*>(
            &kb[buf][row * 32 + ((c ^ r) << 2)]);
      }
#pragma unroll
      for (int h = 0; h < 8; ++h) {
        const int hh = hq * 8 + h;            // hh&7 == h
        qv[h] = *reinterpret_cast<const float4*>(
            &qb[buf][hh * 32 + ((c ^ h) << 2)]);
      }
#pragma unroll
      for (int r = 0; r < 8; ++r)
#pragma unroll
        for (int h = 0; h < 8; ++h)
          DOT4_ACC(acc[r][h], kv[r], qv[h]);
    }
    BAR();                        // all waves done reading buf before overwrite
  }
#undef K2_STAGE
  // fold 4 m-stripes within each lane-quad (ms = lane bits 0-1; quad DPP)
#pragma unroll
  for (int r = 0; r < 8; ++r)
#pragma unroll
    for (int h = 0; h < 8; ++h) {
      acc[r][h] += __shfl_xor(acc[r][h], 1, 64);
      acc[r][h] += __shfl_xor(acc[r][h], 2, 64);
    }
  const float scale = 0.125f;  // 1/sqrt(64); linear -> distributes over m-halves
  float* plane = scp + (size_t)mh * NB * NH * SLEN;
  // lane (ms,rg,hq) writes heads hq*8 + ms*2 + {0,1} for its 8 rows
#pragma unroll
  for (int r = 0; r < 8; ++r) {
#pragma unroll
    for (int t = 0; t < 2; ++t) {
      float v = ms == 0 ? acc[r][t] : ms == 1 ? acc[r][2 + t]
              : ms == 2 ? acc[r][4 + t] : acc[r][6 + t];
      plane[((size_t)b * NH + hq * 8 + ms * 2 + t) * SLEN
            + s0 + w * 64 + rg * 8 + r] = v * scale;
    }
  }
}

// K_SM (R15-identical): sums the two partial planes, softmax, writes plane0.
__global__ __launch_bounds__(256) void k_sm(float* __restrict__ sc0,
                                            const float* __restrict__ sc1) {
  __shared__ float red[8];
  const int tid = threadIdx.x, w = tid >> 6, l = tid & 63;
  float* p0 = sc0 + (size_t)blockIdx.x * SLEN;
  const float* p1 = sc1 + (size_t)blockIdx.x * SLEN;
  float4 xa = reinterpret_cast<const float4*>(p0)[tid];
  float4 xb = reinterpret_cast<const float4*>(p1)[tid];
  float4 x = make_float4(xa.x + xb.x, xa.y + xb.y, xa.z + xb.z, xa.w + xb.w);
  float mx = fmaxf(fmaxf(x.x, x.y), fmaxf(x.z, x.w));
#pragma unroll
  for (int off = 32; off; off >>= 1) mx = fmaxf(mx, __shfl_xor(mx, off, 64));
  if (l == 0) red[w] = mx;
  __syncthreads();
  mx = fmaxf(fmaxf(red[0], red[1]), fmaxf(red[2], red[3]));
  float4 e;
  e.x = __expf(x.x - mx); e.y = __expf(x.y - mx);
  e.z = __expf(x.z - mx); e.w = __expf(x.w - mx);
  float sum = e.x + e.y + e.z + e.w;
  sum = wred_sum(sum);
  if (l == 0) red[4 + w] = sum;
  __syncthreads();
  sum = red[4] + red[5] + red[6] + red[7];
  const float inv = 1.f / sum;
  e.x *= inv; e.y *= inv; e.z *= inv; e.w *= inv;
  reinterpret_cast<float4*>(p0)[tid] = e;
}

// K3 (R15-identical): partial c[ch][b][h][m] = sum_{s in chunk} attn*values.
template <int NCH>
__global__ __launch_bounds__(256) void k3_cpart(const float* __restrict__ values,
                                                const float* __restrict__ attn,
                                                float* __restrict__ cp) {
  constexpr int SC = SLEN / NCH;
  __shared__ __align__(16) float vb[2][4][DMODEL];  // 32 KB
  __shared__ __align__(16) float al[NH][SC];
  const int b = blockIdx.x & 63;
  const int ch = blockIdx.x >> 6;
  const int s0 = ch * SC;
  const int tid = threadIdx.x, w = tid >> 6, l = tid & 63;
  for (int f = tid; f < NH * (SC / 4); f += 256) {
    int hh = f / (SC / 4), c4 = (f % (SC / 4)) * 4;
    *reinterpret_cast<float4*>(&al[hh][c4]) = *reinterpret_cast<const float4*>(
        attn + ((size_t)b * NH + hh) * SLEN + s0 + c4);
  }
  const int m4 = tid * 4;
  float4 acc[NH];
#pragma unroll
  for (int i = 0; i < NH; ++i) acc[i] = make_float4(0.f, 0.f, 0.f, 0.f);
  const size_t rowstride = (size_t)NB * DMODEL;
  const float* vbase = values + ((size_t)s0 * NB + b) * DMODEL;

#define K3_STAGE(buf_, g_) do {                                               \
    const float* rg_ = vbase + (size_t)((g_) * 4 + w) * rowstride;            \
    _Pragma("unroll")                                                         \
    for (int j_ = 0; j_ < 4; ++j_)                                            \
      gload16(rg_ + j_ * 256 + l * 4, &vb[buf_][w][j_ * 256]);                \
  } while (0)

  K3_STAGE(0, 0);
  __syncthreads();  // covers al fill + prologue stage
  for (int g = 0; g < SC / 4; ++g) {
    const int buf = g & 1;
    if (g + 1 < SC / 4) {
      K3_STAGE(buf ^ 1, g + 1);
      VMCNT_WAIT(4);
    } else {
      VMCNT_WAIT(0);
    }
    BAR();
    float4 v0 = *reinterpret_cast<const float4*>(&vb[buf][0][m4]);
    float4 v1 = *reinterpret_cast<const float4*>(&vb[buf][1][m4]);
    float4 v2 = *reinterpret_cast<const float4*>(&vb[buf][2][m4]);
    float4 v3 = *reinterpret_cast<const float4*>(&vb[buf][3][m4]);
#pragma unroll
    for (int hh = 0; hh < NH; ++hh) {
      float4 av = *reinterpret_cast<const float4*>(&al[hh][g * 4]);  // broadcast
      FMA4_BCAST(acc[hh], av, v0, v1, v2, v3);
    }
    BAR();
  }
#undef K3_STAGE
#pragma unroll
  for (int hh = 0; hh < NH; ++hh)
    *reinterpret_cast<float4*>(cp + (((size_t)ch * NB + b) * NH + hh) * DMODEL + m4) = acc[hh];
}

// K4 v2 (R15-identical): out[b][h*64+d] = sum_m Wk[h*64+d][m] * (sum_ch cp).
template <int NCH>
__global__ __launch_bounds__(256) void k4_out(const float* __restrict__ cp,
                                              const float* __restrict__ Wk,
                                              float* __restrict__ out) {
  __shared__ __align__(16) float cl[2 * DMODEL];
  const int h = blockIdx.x & 15;
  const int b0 = (blockIdx.x >> 4) * 2;
  const int tid = threadIdx.x, w = tid >> 6, l = tid & 63;
  for (int f = tid; f < 2 * DMODEL / 4; f += 256) {
    int bi = f >> 8, m4 = (f & 255) * 4;
    float4 s = make_float4(0.f, 0.f, 0.f, 0.f);
#pragma unroll
    for (int ch = 0; ch < NCH; ++ch) {
      float4 t = *reinterpret_cast<const float4*>(
          cp + (((size_t)ch * NB + b0 + bi) * NH + h) * DMODEL + m4);
      s.x += t.x; s.y += t.y; s.z += t.z; s.w += t.w;
    }
    *reinterpret_cast<float4*>(&cl[bi * DMODEL + m4]) = s;
  }
  __syncthreads();
  float4 c[2][4];
#pragma unroll
  for (int bi = 0; bi < 2; ++bi)
#pragma unroll
    for (int k = 0; k < 4; ++k)
      c[bi][k] = *reinterpret_cast<const float4*>(&cl[bi * DMODEL + l * 16 + k * 4]);
  for (int jj = 0; jj < 16; ++jj) {
    const int d = w * 16 + jj;
    const float4* wr = reinterpret_cast<const float4*>(Wk + (size_t)(h * HD + d) * DMODEL) + l * 4;
    const float4 w0 = wr[0], w1 = wr[1], w2 = wr[2], w3 = wr[3];
#pragma unroll
    for (int bi = 0; bi < 2; ++bi) {
      float s = 0.f;
      DOT4_ACC(s, w0, c[bi][0]); DOT4_ACC(s, w1, c[bi][1]);
      DOT4_ACC(s, w2, c[bi][2]); DOT4_ACC(s, w3, c[bi][3]);
      s = wred_sum(s);
      if (l == 0) out[(size_t)(b0 + bi) * (NH * HD) + h * HD + d] = s;
    }
  }
}

extern "C" void kernel_launch(void* const* d_in, const int* in_sizes, int n_in,
                              void* d_out, int out_size, void* d_ws, size_t ws_size,
                              hipStream_t stream) {
  const float* query  = (const float*)d_in[0];
  const float* keys   = (const float*)d_in[1];
  const float* values = (const float*)d_in[2];
  const float* Wq     = (const float*)d_in[3];
  const float* Wk     = (const float*)d_in[4];
  float* out = (float*)d_out;

  float* W   = (float*)d_ws;
  float* qp  = W;                                   // 64*1024
  float* qt  = qp + (size_t)NB * DMODEL;            // 64*16*1024
  float* sc0 = qt + (size_t)NB * NH * DMODEL;       // partial m-half 0 -> attn
  float* sc1 = sc0 + (size_t)NB * NH * SLEN;        // partial m-half 1
  float* cp  = sc1 + (size_t)NB * NH * SLEN;        // NCH*64*16*1024

  const size_t base_floats = (size_t)NB * DMODEL + (size_t)NB * NH * DMODEL
                           + 2 * (size_t)NB * NH * SLEN;

  k0_qp<<<1024, 256, 0, stream>>>(query, Wq, qp);
  k1_qt<<<512, 256, 0, stream>>>(qp, Wk, qt);
  k2_scores<<<512, 256, 0, stream>>>(keys, qt, sc0);  // writes sc0 (mh=0) / sc1 (mh=1)
  k_sm<<<NB * NH, 256, 0, stream>>>(sc0, sc1);

  const size_t chunk_floats = (size_t)NB * NH * DMODEL;
  if (ws_size >= (base_floats + 16 * chunk_floats) * sizeof(float)) {
    k3_cpart<16><<<16 * NB, 256, 0, stream>>>(values, sc0, cp);
    k4_out<16><<<NH * (NB / 2), 256, 0, stream>>>(cp, Wk, out);
  } else if (ws_size >= (base_floats + 8 * chunk_floats) * sizeof(float)) {
    k3_cpart<8><<<8 * NB, 256, 0, stream>>>(values, sc0, cp);
    k4_out<8><<<NH * (NB / 2), 256, 0, stream>>>(cp, Wk, out);
  } else {
    k3_cpart<4><<<4 * NB, 256, 0, stream>>>(values, sc0, cp);
    k4_out<4><<<NH * (NB / 2), 256, 0, stream>>>(cp, Wk, out);
  }
}